// Round 4
// baseline (21171.834 us; speedup 1.0000x reference)
//
#include <hip/hip_runtime.h>

// Time-aware LSTM, persistent-RNN design for MI355X.
// 256 WGs (1/CU) x 256 threads. WG(bg,ug): batches [bg*32,+32), units [ug*16,+16).
// Weights register-resident as MFMA B-fragments (bf16 hi/lo). h exchanged via
// global bf16 hi/lo double buffers; 8 independent 32-WG barriers (per batch-group).
// Plain (non-cooperative) launch: grid(256) <= #CUs(256) => all WGs resident.

using short8 = __attribute__((ext_vector_type(8))) short;
using f32x4  = __attribute__((ext_vector_type(4))) float;

#define TT 512
#define HD 512
#define ED 256

__device__ __forceinline__ short f2bf(float f) {
  unsigned u = __builtin_bit_cast(unsigned, f);
  u = (u + 0x7FFFu + ((u >> 16) & 1u)) >> 16;
  return (short)u;
}
__device__ __forceinline__ float bf2f(short s) {
  unsigned u = ((unsigned)(unsigned short)s) << 16;
  return __builtin_bit_cast(float, u);
}
__device__ __forceinline__ float sigm(float x) { return 1.f / (1.f + __expf(-x)); }
__device__ __forceinline__ float softplusf_(float x) {
  return fmaxf(x, 0.f) + log1pf(__expf(-fabsf(x)));
}

__global__ __launch_bounds__(256, 1) void talstm_scan(
    const int* __restrict__ X, const float* __restrict__ deltas,
    const float* __restrict__ emb,
    const float* __restrict__ Ww, const float* __restrict__ Wb,
    const float* __restrict__ Uw, const float* __restrict__ Ub,
    const float* __restrict__ Wdw, const float* __restrict__ Wdb,
    const float* __restrict__ Udw, const float* __restrict__ Udb,
    float* __restrict__ out, unsigned short* __restrict__ hbuf,
    unsigned int* __restrict__ counters) {
  __shared__ float zp[4][32][81];  // [wave][batch-in-wg][5 gates * 16 units], padded

  const int tid  = threadIdx.x;
  const int wv   = tid >> 6;   // wave 0..3 (k-slice owner)
  const int lane = tid & 63;
  const int l15  = lane & 15;
  const int l4   = lane >> 4;  // 0..3
  const int bg   = blockIdx.x & 7;
  const int ug   = blockIdx.x >> 3;
  const int b0   = bg * 32;
  const int u0   = ug * 16;

  // ---------------- weight fragments (register resident, loaded once) --------
  // B-frag lane l holds B[k0 + l4*8 + j][u0 + l15], j=0..7.
  // h-part k-slice for wave: [wv*128, wv*128+128) -> 4 k-iters of 32.
  // x-part k-slice:          [wv*64,  wv*64+64)   -> 2 k-iters of 32.
  short8 Bhh[5][4], Bhl[5][4], Bx[5][2];
#pragma unroll
  for (int g = 0; g < 5; ++g) {
#pragma unroll
    for (int kit = 0; kit < 4; ++kit) {
      short8 hi, lo;
#pragma unroll
      for (int j = 0; j < 8; ++j) {
        const int kr = wv * 128 + kit * 32 + l4 * 8 + j;
        const float f = (g < 4) ? Uw[kr * 2048 + g * 512 + u0 + l15]
                                : Udw[kr * 512 + u0 + l15];
        const short h16 = f2bf(f);
        hi[j] = h16;
        lo[j] = f2bf(f - bf2f(h16));
      }
      Bhh[g][kit] = hi;
      Bhl[g][kit] = lo;
    }
#pragma unroll
    for (int kit = 0; kit < 2; ++kit) {
      short8 v;
#pragma unroll
      for (int j = 0; j < 8; ++j) {
        const int kr = wv * 64 + kit * 32 + l4 * 8 + j;
        const float f = (g < 4) ? Ww[kr * 2048 + g * 512 + u0 + l15]
                                : Wdw[kr * 512 + u0 + l15];
        v[j] = f2bf(f);
      }
      Bx[g][kit] = v;
    }
  }

  // ---------------- per-thread elementwise state -----------------------------
  // thread owns 2 (b,u) pairs: pr = tid*2+p ; b = pr>>4 (0..31), u = pr&15.
  float bias[2][5];
  float cst[2] = {0.f, 0.f};
  int pb[2], pu[2];
#pragma unroll
  for (int p = 0; p < 2; ++p) {
    const int pr = tid * 2 + p;
    pb[p] = pr >> 4;
    pu[p] = pr & 15;
    const int ugl = u0 + pu[p];
#pragma unroll
    for (int g = 0; g < 4; ++g)
      bias[p][g] = Wb[g * 512 + ugl] + Ub[g * 512 + ugl];
    bias[p][4] = Wdb[ugl] + Udb[ugl];
  }

  unsigned int* cnt = counters + bg * 64;  // one cacheline per batch-group

  // x fragments for t = 0 (prefetched thereafter)
  short8 ax[2][2];
#pragma unroll
  for (int m = 0; m < 2; ++m) {
    const int b = b0 + m * 16 + l15;
    const int xi = X[b * TT + 0];
    const float* er = emb + (size_t)xi * ED + wv * 64 + l4 * 8;
#pragma unroll
    for (int kit = 0; kit < 2; ++kit) {
      f32x4 f0 = *(const f32x4*)(er + kit * 32);
      f32x4 f1 = *(const f32x4*)(er + kit * 32 + 4);
      short8 v;
      v[0] = f2bf(f0[0]); v[1] = f2bf(f0[1]); v[2] = f2bf(f0[2]); v[3] = f2bf(f0[3]);
      v[4] = f2bf(f1[0]); v[5] = f2bf(f1[1]); v[6] = f2bf(f1[2]); v[7] = f2bf(f1[3]);
      ax[m][kit] = v;
    }
  }

  for (int t = 0; t < TT; ++t) {
    // ---- wait until all 32 WGs of this batch-group finished step t-1 ----
    if (t > 0) {
      if (tid == 0) {
        const unsigned tgt = 32u * (unsigned)t;
        while (__hip_atomic_load(cnt, __ATOMIC_ACQUIRE, __HIP_MEMORY_SCOPE_AGENT) < tgt)
          __builtin_amdgcn_s_sleep(2);
      }
      __syncthreads();
      __builtin_amdgcn_fence(__ATOMIC_ACQUIRE, "agent");
    }

    // ---- load h fragments (hi/lo) for this wave's k-slice ----
    const unsigned short* hh = hbuf + (size_t)(t & 1) * 262144;
    const unsigned short* hl = hh + 131072;
    short8 ahh[2][4], ahl[2][4];
#pragma unroll
    for (int m = 0; m < 2; ++m) {
      const int b = b0 + m * 16 + l15;
      const unsigned short* rh = hh + b * HD + wv * 128 + l4 * 8;
      const unsigned short* rl = hl + b * HD + wv * 128 + l4 * 8;
#pragma unroll
      for (int kit = 0; kit < 4; ++kit) {
        ahh[m][kit] = *(const short8*)(rh + kit * 32);
        ahl[m][kit] = *(const short8*)(rl + kit * 32);
      }
    }

    f32x4 acc[2][5];
#pragma unroll
    for (int m = 0; m < 2; ++m)
#pragma unroll
      for (int g = 0; g < 5; ++g) {
        f32x4 z0 = {0.f, 0.f, 0.f, 0.f};
        acc[m][g] = z0;
      }

    // ---- x contribution (fragments already resident) ----
#pragma unroll
    for (int kit = 0; kit < 2; ++kit)
#pragma unroll
      for (int m = 0; m < 2; ++m)
#pragma unroll
        for (int g = 0; g < 5; ++g)
          acc[m][g] = __builtin_amdgcn_mfma_f32_16x16x32_bf16(
              ax[m][kit], Bx[g][kit], acc[m][g], 0, 0, 0);

    // ---- h contribution: 3-term hi/lo for ~fp32-grade accuracy ----
#pragma unroll
    for (int kit = 0; kit < 4; ++kit) {
#pragma unroll
      for (int m = 0; m < 2; ++m)
#pragma unroll
        for (int g = 0; g < 5; ++g)
          acc[m][g] = __builtin_amdgcn_mfma_f32_16x16x32_bf16(
              ahh[m][kit], Bhh[g][kit], acc[m][g], 0, 0, 0);
#pragma unroll
      for (int m = 0; m < 2; ++m)
#pragma unroll
        for (int g = 0; g < 5; ++g)
          acc[m][g] = __builtin_amdgcn_mfma_f32_16x16x32_bf16(
              ahl[m][kit], Bhh[g][kit], acc[m][g], 0, 0, 0);
#pragma unroll
      for (int m = 0; m < 2; ++m)
#pragma unroll
        for (int g = 0; g < 5; ++g)
          acc[m][g] = __builtin_amdgcn_mfma_f32_16x16x32_bf16(
              ahh[m][kit], Bhl[g][kit], acc[m][g], 0, 0, 0);
    }

    // ---- write k-partials to LDS ----
#pragma unroll
    for (int m = 0; m < 2; ++m)
#pragma unroll
      for (int g = 0; g < 5; ++g)
#pragma unroll
        for (int r = 0; r < 4; ++r)
          zp[wv][m * 16 + l4 * 4 + r][g * 16 + l15] = acc[m][g][r];
    __syncthreads();

    // ---- prefetch x fragments for t+1 (overlaps elementwise) ----
    if (t + 1 < TT) {
#pragma unroll
      for (int m = 0; m < 2; ++m) {
        const int b = b0 + m * 16 + l15;
        const int xi = X[b * TT + (t + 1)];
        const float* er = emb + (size_t)xi * ED + wv * 64 + l4 * 8;
#pragma unroll
        for (int kit = 0; kit < 2; ++kit) {
          f32x4 f0 = *(const f32x4*)(er + kit * 32);
          f32x4 f1 = *(const f32x4*)(er + kit * 32 + 4);
          short8 v;
          v[0] = f2bf(f0[0]); v[1] = f2bf(f0[1]); v[2] = f2bf(f0[2]); v[3] = f2bf(f0[3]);
          v[4] = f2bf(f1[0]); v[5] = f2bf(f1[1]); v[6] = f2bf(f1[2]); v[7] = f2bf(f1[3]);
          ax[m][kit] = v;
        }
      }
    }

    // ---- elementwise LSTM update (f32) ----
    unsigned short* wh = hbuf + (size_t)((t + 1) & 1) * 262144;
#pragma unroll
    for (int p = 0; p < 2; ++p) {
      float z[5];
#pragma unroll
      for (int g = 0; g < 5; ++g) {
        const int cidx = g * 16 + pu[p];
        z[g] = zp[0][pb[p]][cidx] + zp[1][pb[p]][cidx] + zp[2][pb[p]][cidx] +
               zp[3][pb[p]][cidx] + bias[p][g];
      }
      const int bglo = b0 + pb[p];
      const float dt = deltas[bglo * TT + t];
      const float ii = sigm(z[0]);
      const float ff = sigm(z[1]);
      const float oo = sigm(z[2]);
      const float gg = tanhf(z[3]);
      const float dd = softplusf_(z[4]);
      const float gamma = __expf(-dd * dt);
      const float c = ff * (gamma * cst[p]) + ii * gg;
      cst[p] = c;
      const float h = oo * tanhf(c);
      const int ugl = u0 + pu[p];
      const short hv = f2bf(h);
      const short lv = f2bf(h - bf2f(hv));
      wh[bglo * HD + ugl] = (unsigned short)hv;
      wh[131072 + bglo * HD + ugl] = (unsigned short)lv;
      if (t == TT - 1) out[256 + bglo * HD + ugl] = h;
    }

    // ---- publish h and arrive at batch-group barrier ----
    __threadfence();
    __syncthreads();
    if (tid == 0)
      __hip_atomic_fetch_add(cnt, 1u, __ATOMIC_RELEASE, __HIP_MEMORY_SCOPE_AGENT);
  }
}

__global__ __launch_bounds__(256) void logits_k(const float* __restrict__ fcw,
                                                const float* __restrict__ fcb,
                                                float* __restrict__ out) {
  const int b = blockIdx.x * 4 + (threadIdx.x >> 6);
  const int lane = threadIdx.x & 63;
  const float* h = out + 256 + b * HD;
  float s = 0.f;
#pragma unroll
  for (int u = 0; u < 8; ++u) s += h[lane + u * 64] * fcw[lane + u * 64];
#pragma unroll
  for (int off = 32; off > 0; off >>= 1) s += __shfl_down(s, off, 64);
  if (lane == 0) out[b] = s + fcb[0];
}

extern "C" void kernel_launch(void* const* d_in, const int* in_sizes, int n_in,
                              void* d_out, int out_size, void* d_ws, size_t ws_size,
                              hipStream_t stream) {
  (void)in_sizes; (void)n_in; (void)out_size; (void)ws_size;
  const int* X        = (const int*)d_in[0];
  // d_in[1] = M (all-ones mask, unused by reference)
  const float* deltas = (const float*)d_in[2];
  const float* emb    = (const float*)d_in[3];
  const float* Ww     = (const float*)d_in[4];
  const float* Wb     = (const float*)d_in[5];
  const float* Uw     = (const float*)d_in[6];
  const float* Ub     = (const float*)d_in[7];
  const float* Wdw    = (const float*)d_in[8];
  const float* Wdb    = (const float*)d_in[9];
  const float* Udw    = (const float*)d_in[10];
  const float* Udb    = (const float*)d_in[11];
  const float* fcw    = (const float*)d_in[12];
  const float* fcb    = (const float*)d_in[13];
  float* out          = (float*)d_out;

  unsigned short* hbuf     = (unsigned short*)d_ws;
  unsigned int*   counters = (unsigned int*)((char*)d_ws + (1 << 20));

  // zero h buffer 0 (hi+lo) and the barrier counters
  (void)hipMemsetAsync(d_ws, 0, 524288, stream);
  (void)hipMemsetAsync((char*)d_ws + (1 << 20), 0, 4096, stream);

  // Plain launch: 256 WGs <= 256 CUs, each fits (LDS 41KB, <=512 VGPR/wave),
  // so all WGs are resident and the inter-WG spin barrier cannot starve.
  hipLaunchKernelGGL(talstm_scan, dim3(256), dim3(256), 0, stream,
                     X, deltas, emb, Ww, Wb, Uw, Ub, Wdw, Wdb, Udw, Udb,
                     out, hbuf, counters);
  hipLaunchKernelGGL(logits_k, dim3(64), dim3(256), 0, stream, fcw, fcb, out);
}

// Round 5
// 15531.808 us; speedup vs baseline: 1.3631x; 1.3631x over previous
//
#include <hip/hip_runtime.h>

// Time-aware LSTM, persistent-RNN design for MI355X.
// 256 WGs (1/CU) x 256 threads. WG(bg,ug): batches [bg*32,+32), units [ug*16,+16).
// Weights register-resident as MFMA B-fragments (bf16 hi/lo). h exchanged via
// global bf16 hi/lo double buffers.
// Sync: per-WG flag words (no RMW). Wave 0 polls its group's 32 flags with
// RELAXED loads (no per-poll cache invalidate!), one acquire fence per step.
// Release side: one release fence, then a relaxed flag store. This avoids the
// per-poll buffer_inv L2-nuke that made the atomic-counter version 41us/step.

using short8 = __attribute__((ext_vector_type(8))) short;
using f32x4  = __attribute__((ext_vector_type(4))) float;

#define TT 512
#define HD 512
#define ED 256

__device__ __forceinline__ short f2bf(float f) {
  unsigned u = __builtin_bit_cast(unsigned, f);
  u = (u + 0x7FFFu + ((u >> 16) & 1u)) >> 16;
  return (short)u;
}
__device__ __forceinline__ float bf2f(short s) {
  unsigned u = ((unsigned)(unsigned short)s) << 16;
  return __builtin_bit_cast(float, u);
}
__device__ __forceinline__ float sigm(float x) { return 1.f / (1.f + __expf(-x)); }
__device__ __forceinline__ float softplusf_(float x) {
  return fmaxf(x, 0.f) + log1pf(__expf(-fabsf(x)));
}

__global__ __launch_bounds__(256, 1) void talstm_scan(
    const int* __restrict__ X, const float* __restrict__ deltas,
    const float* __restrict__ emb,
    const float* __restrict__ Ww, const float* __restrict__ Wb,
    const float* __restrict__ Uw, const float* __restrict__ Ub,
    const float* __restrict__ Wdw, const float* __restrict__ Wdb,
    const float* __restrict__ Udw, const float* __restrict__ Udb,
    float* __restrict__ out, unsigned short* __restrict__ hbuf,
    unsigned int* __restrict__ flags) {
  __shared__ float zp[4][32][81];  // [wave][batch-in-wg][5 gates * 16 units], padded

  const int tid  = threadIdx.x;
  const int wv   = tid >> 6;   // wave 0..3 (k-slice owner)
  const int lane = tid & 63;
  const int l15  = lane & 15;
  const int l4   = lane >> 4;  // 0..3
  const int bg   = blockIdx.x & 7;
  const int ug   = blockIdx.x >> 3;
  const int b0   = bg * 32;
  const int u0   = ug * 16;

  // ---------------- weight fragments (register resident, loaded once) --------
  short8 Bhh[5][4], Bhl[5][4], Bx[5][2];
#pragma unroll
  for (int g = 0; g < 5; ++g) {
#pragma unroll
    for (int kit = 0; kit < 4; ++kit) {
      short8 hi, lo;
#pragma unroll
      for (int j = 0; j < 8; ++j) {
        const int kr = wv * 128 + kit * 32 + l4 * 8 + j;
        const float f = (g < 4) ? Uw[kr * 2048 + g * 512 + u0 + l15]
                                : Udw[kr * 512 + u0 + l15];
        const short h16 = f2bf(f);
        hi[j] = h16;
        lo[j] = f2bf(f - bf2f(h16));
      }
      Bhh[g][kit] = hi;
      Bhl[g][kit] = lo;
    }
#pragma unroll
    for (int kit = 0; kit < 2; ++kit) {
      short8 v;
#pragma unroll
      for (int j = 0; j < 8; ++j) {
        const int kr = wv * 64 + kit * 32 + l4 * 8 + j;
        const float f = (g < 4) ? Ww[kr * 2048 + g * 512 + u0 + l15]
                                : Wdw[kr * 512 + u0 + l15];
        v[j] = f2bf(f);
      }
      Bx[g][kit] = v;
    }
  }

  // ---------------- per-thread elementwise state -----------------------------
  // thread owns units (pu0, pu0+1) of batch pb0: pb0 = tid>>3, pu0 = (tid*2)&15.
  const int pb0  = (tid * 2) >> 4;  // 0..31
  const int pu0  = (tid * 2) & 15;  // even
  const int bglo = b0 + pb0;
  const int ugl0 = u0 + pu0;
  float bias[2][5];
  float cst[2] = {0.f, 0.f};
#pragma unroll
  for (int p = 0; p < 2; ++p) {
    const int ugl = ugl0 + p;
#pragma unroll
    for (int g = 0; g < 4; ++g)
      bias[p][g] = Wb[g * 512 + ugl] + Ub[g * 512 + ugl];
    bias[p][4] = Wdb[ugl] + Udb[ugl];
  }

  unsigned int* grp_flags = flags + bg * 32;  // 32 flags = one 128B line
  unsigned int* my_flag   = flags + bg * 32 + ug;

  // x fragments for t = 0 (prefetched thereafter)
  short8 ax[2][2];
#pragma unroll
  for (int m = 0; m < 2; ++m) {
    const int b = b0 + m * 16 + l15;
    const int xi = X[b * TT + 0];
    const float* er = emb + (size_t)xi * ED + wv * 64 + l4 * 8;
#pragma unroll
    for (int kit = 0; kit < 2; ++kit) {
      f32x4 f0 = *(const f32x4*)(er + kit * 32);
      f32x4 f1 = *(const f32x4*)(er + kit * 32 + 4);
      short8 v;
      v[0] = f2bf(f0[0]); v[1] = f2bf(f0[1]); v[2] = f2bf(f0[2]); v[3] = f2bf(f0[3]);
      v[4] = f2bf(f1[0]); v[5] = f2bf(f1[1]); v[6] = f2bf(f1[2]); v[7] = f2bf(f1[3]);
      ax[m][kit] = v;
    }
  }

  for (int t = 0; t < TT; ++t) {
    // ---- wait until all 32 WGs of this batch-group finished step t-1 ----
    if (t > 0) {
      if (wv == 0) {
        const unsigned tgt = (unsigned)t;
        for (;;) {
          unsigned v = tgt;
          if (lane < 32)
            v = __hip_atomic_load(grp_flags + lane, __ATOMIC_RELAXED,
                                  __HIP_MEMORY_SCOPE_AGENT);
          if (__all(v >= tgt)) break;
          __builtin_amdgcn_s_sleep(1);
        }
      }
      __syncthreads();
      __builtin_amdgcn_fence(__ATOMIC_ACQUIRE, "agent");
    }

    // ---- load h fragments (hi/lo) for this wave's k-slice ----
    const unsigned short* hh = hbuf + (size_t)(t & 1) * 262144;
    const unsigned short* hl = hh + 131072;
    short8 ahh[2][4], ahl[2][4];
#pragma unroll
    for (int m = 0; m < 2; ++m) {
      const int b = b0 + m * 16 + l15;
      const unsigned short* rh = hh + b * HD + wv * 128 + l4 * 8;
      const unsigned short* rl = hl + b * HD + wv * 128 + l4 * 8;
#pragma unroll
      for (int kit = 0; kit < 4; ++kit) {
        ahh[m][kit] = *(const short8*)(rh + kit * 32);
        ahl[m][kit] = *(const short8*)(rl + kit * 32);
      }
    }

    f32x4 acc[2][5];
#pragma unroll
    for (int m = 0; m < 2; ++m)
#pragma unroll
      for (int g = 0; g < 5; ++g) {
        f32x4 z0 = {0.f, 0.f, 0.f, 0.f};
        acc[m][g] = z0;
      }

    // ---- x contribution (fragments already resident) ----
#pragma unroll
    for (int kit = 0; kit < 2; ++kit)
#pragma unroll
      for (int m = 0; m < 2; ++m)
#pragma unroll
        for (int g = 0; g < 5; ++g)
          acc[m][g] = __builtin_amdgcn_mfma_f32_16x16x32_bf16(
              ax[m][kit], Bx[g][kit], acc[m][g], 0, 0, 0);

    // ---- h contribution: 3-term hi/lo for ~fp32-grade accuracy ----
#pragma unroll
    for (int kit = 0; kit < 4; ++kit) {
#pragma unroll
      for (int m = 0; m < 2; ++m)
#pragma unroll
        for (int g = 0; g < 5; ++g)
          acc[m][g] = __builtin_amdgcn_mfma_f32_16x16x32_bf16(
              ahh[m][kit], Bhh[g][kit], acc[m][g], 0, 0, 0);
#pragma unroll
      for (int m = 0; m < 2; ++m)
#pragma unroll
        for (int g = 0; g < 5; ++g)
          acc[m][g] = __builtin_amdgcn_mfma_f32_16x16x32_bf16(
              ahl[m][kit], Bhh[g][kit], acc[m][g], 0, 0, 0);
#pragma unroll
      for (int m = 0; m < 2; ++m)
#pragma unroll
        for (int g = 0; g < 5; ++g)
          acc[m][g] = __builtin_amdgcn_mfma_f32_16x16x32_bf16(
              ahh[m][kit], Bhl[g][kit], acc[m][g], 0, 0, 0);
    }

    // ---- write k-partials to LDS ----
#pragma unroll
    for (int m = 0; m < 2; ++m)
#pragma unroll
      for (int g = 0; g < 5; ++g)
#pragma unroll
        for (int r = 0; r < 4; ++r)
          zp[wv][m * 16 + l4 * 4 + r][g * 16 + l15] = acc[m][g][r];
    __syncthreads();

    // ---- prefetch x fragments for t+1 (overlaps elementwise) ----
    if (t + 1 < TT) {
#pragma unroll
      for (int m = 0; m < 2; ++m) {
        const int b = b0 + m * 16 + l15;
        const int xi = X[b * TT + (t + 1)];
        const float* er = emb + (size_t)xi * ED + wv * 64 + l4 * 8;
#pragma unroll
        for (int kit = 0; kit < 2; ++kit) {
          f32x4 f0 = *(const f32x4*)(er + kit * 32);
          f32x4 f1 = *(const f32x4*)(er + kit * 32 + 4);
          short8 v;
          v[0] = f2bf(f0[0]); v[1] = f2bf(f0[1]); v[2] = f2bf(f0[2]); v[3] = f2bf(f0[3]);
          v[4] = f2bf(f1[0]); v[5] = f2bf(f1[1]); v[6] = f2bf(f1[2]); v[7] = f2bf(f1[3]);
          ax[m][kit] = v;
        }
      }
    }

    // ---- elementwise LSTM update (f32), 2 adjacent units of one batch ----
    unsigned short* wh = hbuf + (size_t)((t + 1) & 1) * 262144;
    const float dt = deltas[bglo * TT + t];
    unsigned short hv[2], lv[2];
    float hval[2];
#pragma unroll
    for (int p = 0; p < 2; ++p) {
      float z[5];
#pragma unroll
      for (int g = 0; g < 5; ++g) {
        const int cidx = g * 16 + pu0 + p;
        z[g] = zp[0][pb0][cidx] + zp[1][pb0][cidx] + zp[2][pb0][cidx] +
               zp[3][pb0][cidx] + bias[p][g];
      }
      const float ii = sigm(z[0]);
      const float ff = sigm(z[1]);
      const float oo = sigm(z[2]);
      const float gg = tanhf(z[3]);
      const float dd = softplusf_(z[4]);
      const float gamma = __expf(-dd * dt);
      const float c = ff * (gamma * cst[p]) + ii * gg;
      cst[p] = c;
      const float h = oo * tanhf(c);
      hval[p] = h;
      const short hvs = f2bf(h);
      hv[p] = (unsigned short)hvs;
      lv[p] = (unsigned short)f2bf(h - bf2f(hvs));
    }
    *(unsigned*)(wh + bglo * HD + ugl0) =
        (unsigned)hv[0] | ((unsigned)hv[1] << 16);
    *(unsigned*)(wh + 131072 + bglo * HD + ugl0) =
        (unsigned)lv[0] | ((unsigned)lv[1] << 16);
    if (t == TT - 1) {
      float2 hv2 = make_float2(hval[0], hval[1]);
      *(float2*)(out + 256 + bglo * HD + ugl0) = hv2;
    }

    // ---- publish h: release fence, then set own flag (no RMW) ----
    __builtin_amdgcn_fence(__ATOMIC_RELEASE, "agent");
    __syncthreads();
    if (tid == 0)
      __hip_atomic_store(my_flag, (unsigned)(t + 1), __ATOMIC_RELAXED,
                         __HIP_MEMORY_SCOPE_AGENT);
  }
}

__global__ __launch_bounds__(256) void logits_k(const float* __restrict__ fcw,
                                                const float* __restrict__ fcb,
                                                float* __restrict__ out) {
  const int b = blockIdx.x * 4 + (threadIdx.x >> 6);
  const int lane = threadIdx.x & 63;
  const float* h = out + 256 + b * HD;
  float s = 0.f;
#pragma unroll
  for (int u = 0; u < 8; ++u) s += h[lane + u * 64] * fcw[lane + u * 64];
#pragma unroll
  for (int off = 32; off > 0; off >>= 1) s += __shfl_down(s, off, 64);
  if (lane == 0) out[b] = s + fcb[0];
}

extern "C" void kernel_launch(void* const* d_in, const int* in_sizes, int n_in,
                              void* d_out, int out_size, void* d_ws, size_t ws_size,
                              hipStream_t stream) {
  (void)in_sizes; (void)n_in; (void)out_size; (void)ws_size;
  const int* X        = (const int*)d_in[0];
  // d_in[1] = M (all-ones mask, unused by reference)
  const float* deltas = (const float*)d_in[2];
  const float* emb    = (const float*)d_in[3];
  const float* Ww     = (const float*)d_in[4];
  const float* Wb     = (const float*)d_in[5];
  const float* Uw     = (const float*)d_in[6];
  const float* Ub     = (const float*)d_in[7];
  const float* Wdw    = (const float*)d_in[8];
  const float* Wdb    = (const float*)d_in[9];
  const float* Udw    = (const float*)d_in[10];
  const float* Udb    = (const float*)d_in[11];
  const float* fcw    = (const float*)d_in[12];
  const float* fcb    = (const float*)d_in[13];
  float* out          = (float*)d_out;

  unsigned short* hbuf  = (unsigned short*)d_ws;
  unsigned int*   flags = (unsigned int*)((char*)d_ws + (1 << 20));

  // zero h buffer 0 (hi+lo) and the flags
  (void)hipMemsetAsync(d_ws, 0, 524288, stream);
  (void)hipMemsetAsync((char*)d_ws + (1 << 20), 0, 4096, stream);

  // Plain launch: 256 WGs <= 256 CUs, each fits (LDS 41KB, <=512 VGPR/wave),
  // so all WGs are resident and the inter-WG spin barrier cannot starve.
  hipLaunchKernelGGL(talstm_scan, dim3(256), dim3(256), 0, stream,
                     X, deltas, emb, Ww, Wb, Uw, Ub, Wdw, Wdb, Udw, Udb,
                     out, hbuf, flags);
  hipLaunchKernelGGL(logits_k, dim3(64), dim3(256), 0, stream, fcw, fcb, out);
}

// Round 6
// 3983.271 us; speedup vs baseline: 5.3152x; 3.8993x over previous
//
#include <hip/hip_runtime.h>

// Time-aware LSTM, persistent-RNN design for MI355X.
// 256 WGs (1/CU) x 256 threads. WG(bg,ug): batches [bg*32,+32), units [ug*16,+16).
// Weights register-resident as MFMA B-fragments (bf16 hi/lo).
// h exchange: per-instruction coherent (sc0 sc1 = bypass L1/L2, served at the
// XCD-shared Infinity Cache). NO agent-scope fences anywhere in the loop --
// V5's buffer_wbl2/buffer_inv per step flushed h to HBM every step (~30us/step).
// Ordering: h stores -> s_waitcnt vmcnt(0) -> syncthreads -> relaxed flag store;
// consumer polls flags (relaxed) then reads h with cache-bypassing loads.

using short8 = __attribute__((ext_vector_type(8))) short;
using f32x4  = __attribute__((ext_vector_type(4))) float;

#define TT 512
#define HD 512
#define ED 256

__device__ __forceinline__ short f2bf(float f) {
  unsigned u = __builtin_bit_cast(unsigned, f);
  u = (u + 0x7FFFu + ((u >> 16) & 1u)) >> 16;
  return (short)u;
}
__device__ __forceinline__ float bf2f(short s) {
  unsigned u = ((unsigned)(unsigned short)s) << 16;
  return __builtin_bit_cast(float, u);
}
__device__ __forceinline__ float sigm(float x) { return 1.f / (1.f + __expf(-x)); }
__device__ __forceinline__ float softplusf_(float x) {
  return fmaxf(x, 0.f) + log1pf(__expf(-fabsf(x)));
}

// Coherent (device-scope, L1/L2-bypassing) 16B load / 4B store.
__device__ __forceinline__ short8 ld_cohx4(const unsigned short* p) {
  short8 v;
  asm volatile("global_load_dwordx4 %0, %1, off sc0 sc1"
               : "=v"(v) : "v"(p) : "memory");
  return v;
}
__device__ __forceinline__ void st_coh(unsigned* p, unsigned v) {
  asm volatile("global_store_dword %0, %1, off sc0 sc1"
               :: "v"(p), "v"(v) : "memory");
}

__global__ __launch_bounds__(256, 1) void talstm_scan(
    const int* __restrict__ X, const float* __restrict__ deltas,
    const float* __restrict__ emb,
    const float* __restrict__ Ww, const float* __restrict__ Wb,
    const float* __restrict__ Uw, const float* __restrict__ Ub,
    const float* __restrict__ Wdw, const float* __restrict__ Wdb,
    const float* __restrict__ Udw, const float* __restrict__ Udb,
    float* __restrict__ out, unsigned short* __restrict__ hbuf,
    unsigned int* __restrict__ flags) {
  __shared__ float zp[4][32][81];  // [wave][batch-in-wg][5 gates * 16 units], padded

  const int tid  = threadIdx.x;
  const int wv   = tid >> 6;   // wave 0..3 (k-slice owner)
  const int lane = tid & 63;
  const int l15  = lane & 15;
  const int l4   = lane >> 4;  // 0..3
  const int bg   = blockIdx.x & 7;
  const int ug   = blockIdx.x >> 3;
  const int b0   = bg * 32;
  const int u0   = ug * 16;

  // ---------------- weight fragments (register resident, loaded once) --------
  short8 Bhh[5][4], Bhl[5][4], Bx[5][2];
#pragma unroll
  for (int g = 0; g < 5; ++g) {
#pragma unroll
    for (int kit = 0; kit < 4; ++kit) {
      short8 hi, lo;
#pragma unroll
      for (int j = 0; j < 8; ++j) {
        const int kr = wv * 128 + kit * 32 + l4 * 8 + j;
        const float f = (g < 4) ? Uw[kr * 2048 + g * 512 + u0 + l15]
                                : Udw[kr * 512 + u0 + l15];
        const short h16 = f2bf(f);
        hi[j] = h16;
        lo[j] = f2bf(f - bf2f(h16));
      }
      Bhh[g][kit] = hi;
      Bhl[g][kit] = lo;
    }
#pragma unroll
    for (int kit = 0; kit < 2; ++kit) {
      short8 v;
#pragma unroll
      for (int j = 0; j < 8; ++j) {
        const int kr = wv * 64 + kit * 32 + l4 * 8 + j;
        const float f = (g < 4) ? Ww[kr * 2048 + g * 512 + u0 + l15]
                                : Wdw[kr * 512 + u0 + l15];
        v[j] = f2bf(f);
      }
      Bx[g][kit] = v;
    }
  }

  // ---------------- per-thread elementwise state -----------------------------
  const int pb0  = (tid * 2) >> 4;  // 0..31
  const int pu0  = (tid * 2) & 15;  // even
  const int bglo = b0 + pb0;
  const int ugl0 = u0 + pu0;
  float bias[2][5];
  float cst[2] = {0.f, 0.f};
#pragma unroll
  for (int p = 0; p < 2; ++p) {
    const int ugl = ugl0 + p;
#pragma unroll
    for (int g = 0; g < 4; ++g)
      bias[p][g] = Wb[g * 512 + ugl] + Ub[g * 512 + ugl];
    bias[p][4] = Wdb[ugl] + Udb[ugl];
  }

  unsigned int* grp_flags = flags + bg * 32;  // 32 flags = one 128B line
  unsigned int* my_flag   = flags + bg * 32 + ug;

  // x fragments for t = 0 (prefetched thereafter)
  short8 ax[2][2];
#pragma unroll
  for (int m = 0; m < 2; ++m) {
    const int b = b0 + m * 16 + l15;
    const int xi = X[b * TT + 0];
    const float* er = emb + (size_t)xi * ED + wv * 64 + l4 * 8;
#pragma unroll
    for (int kit = 0; kit < 2; ++kit) {
      f32x4 f0 = *(const f32x4*)(er + kit * 32);
      f32x4 f1 = *(const f32x4*)(er + kit * 32 + 4);
      short8 v;
      v[0] = f2bf(f0[0]); v[1] = f2bf(f0[1]); v[2] = f2bf(f0[2]); v[3] = f2bf(f0[3]);
      v[4] = f2bf(f1[0]); v[5] = f2bf(f1[1]); v[6] = f2bf(f1[2]); v[7] = f2bf(f1[3]);
      ax[m][kit] = v;
    }
  }

  for (int t = 0; t < TT; ++t) {
    // ---- wait until all 32 WGs of this batch-group finished step t-1 ----
    if (t > 0) {
      if (wv == 0) {
        const unsigned tgt = (unsigned)t;
        for (;;) {
          unsigned v = tgt;
          if (lane < 32)
            v = __hip_atomic_load(grp_flags + lane, __ATOMIC_RELAXED,
                                  __HIP_MEMORY_SCOPE_AGENT);
          if (__all(v >= tgt)) break;
          __builtin_amdgcn_s_sleep(1);
        }
      }
      __syncthreads();
    }

    // ---- load h fragments (hi/lo): coherent loads, fresh from L3 ----
    const unsigned short* hh = hbuf + (size_t)(t & 1) * 262144;
    const unsigned short* hl = hh + 131072;
    short8 ahh[2][4], ahl[2][4];
#pragma unroll
    for (int m = 0; m < 2; ++m) {
      const int b = b0 + m * 16 + l15;
      const unsigned short* rh = hh + b * HD + wv * 128 + l4 * 8;
      const unsigned short* rl = hl + b * HD + wv * 128 + l4 * 8;
#pragma unroll
      for (int kit = 0; kit < 4; ++kit) {
        ahh[m][kit] = ld_cohx4(rh + kit * 32);
        ahl[m][kit] = ld_cohx4(rl + kit * 32);
      }
    }
    // asm loads are invisible to the compiler's waitcnt tracking: drain
    // explicitly, and fence the scheduler so MFMAs can't hoist above (rule #18).
    asm volatile("s_waitcnt vmcnt(0)" ::: "memory");
    __builtin_amdgcn_sched_barrier(0);

    f32x4 acc[2][5];
#pragma unroll
    for (int m = 0; m < 2; ++m)
#pragma unroll
      for (int g = 0; g < 5; ++g) {
        f32x4 z0 = {0.f, 0.f, 0.f, 0.f};
        acc[m][g] = z0;
      }

    // ---- x contribution (fragments already resident) ----
#pragma unroll
    for (int kit = 0; kit < 2; ++kit)
#pragma unroll
      for (int m = 0; m < 2; ++m)
#pragma unroll
        for (int g = 0; g < 5; ++g)
          acc[m][g] = __builtin_amdgcn_mfma_f32_16x16x32_bf16(
              ax[m][kit], Bx[g][kit], acc[m][g], 0, 0, 0);

    // ---- h contribution: 3-term hi/lo for ~fp32-grade accuracy ----
#pragma unroll
    for (int kit = 0; kit < 4; ++kit) {
#pragma unroll
      for (int m = 0; m < 2; ++m)
#pragma unroll
        for (int g = 0; g < 5; ++g)
          acc[m][g] = __builtin_amdgcn_mfma_f32_16x16x32_bf16(
              ahh[m][kit], Bhh[g][kit], acc[m][g], 0, 0, 0);
#pragma unroll
      for (int m = 0; m < 2; ++m)
#pragma unroll
        for (int g = 0; g < 5; ++g)
          acc[m][g] = __builtin_amdgcn_mfma_f32_16x16x32_bf16(
              ahl[m][kit], Bhh[g][kit], acc[m][g], 0, 0, 0);
#pragma unroll
      for (int m = 0; m < 2; ++m)
#pragma unroll
        for (int g = 0; g < 5; ++g)
          acc[m][g] = __builtin_amdgcn_mfma_f32_16x16x32_bf16(
              ahh[m][kit], Bhl[g][kit], acc[m][g], 0, 0, 0);
    }

    // ---- write k-partials to LDS ----
#pragma unroll
    for (int m = 0; m < 2; ++m)
#pragma unroll
      for (int g = 0; g < 5; ++g)
#pragma unroll
        for (int r = 0; r < 4; ++r)
          zp[wv][m * 16 + l4 * 4 + r][g * 16 + l15] = acc[m][g][r];
    __syncthreads();

    // ---- prefetch x fragments for t+1 (overlaps elementwise) ----
    if (t + 1 < TT) {
#pragma unroll
      for (int m = 0; m < 2; ++m) {
        const int b = b0 + m * 16 + l15;
        const int xi = X[b * TT + (t + 1)];
        const float* er = emb + (size_t)xi * ED + wv * 64 + l4 * 8;
#pragma unroll
        for (int kit = 0; kit < 2; ++kit) {
          f32x4 f0 = *(const f32x4*)(er + kit * 32);
          f32x4 f1 = *(const f32x4*)(er + kit * 32 + 4);
          short8 v;
          v[0] = f2bf(f0[0]); v[1] = f2bf(f0[1]); v[2] = f2bf(f0[2]); v[3] = f2bf(f0[3]);
          v[4] = f2bf(f1[0]); v[5] = f2bf(f1[1]); v[6] = f2bf(f1[2]); v[7] = f2bf(f1[3]);
          ax[m][kit] = v;
        }
      }
    }

    // ---- elementwise LSTM update (f32), 2 adjacent units of one batch ----
    unsigned short* wh = hbuf + (size_t)((t + 1) & 1) * 262144;
    const float dt = deltas[bglo * TT + t];
    unsigned short hv[2], lv[2];
    float hval[2];
#pragma unroll
    for (int p = 0; p < 2; ++p) {
      float z[5];
#pragma unroll
      for (int g = 0; g < 5; ++g) {
        const int cidx = g * 16 + pu0 + p;
        z[g] = zp[0][pb0][cidx] + zp[1][pb0][cidx] + zp[2][pb0][cidx] +
               zp[3][pb0][cidx] + bias[p][g];
      }
      const float ii = sigm(z[0]);
      const float ff = sigm(z[1]);
      const float oo = sigm(z[2]);
      const float gg = tanhf(z[3]);
      const float dd = softplusf_(z[4]);
      const float gamma = __expf(-dd * dt);
      const float c = ff * (gamma * cst[p]) + ii * gg;
      cst[p] = c;
      const float h = oo * tanhf(c);
      hval[p] = h;
      const short hvs = f2bf(h);
      hv[p] = (unsigned short)hvs;
      lv[p] = (unsigned short)f2bf(h - bf2f(hvs));
    }
    // coherent write-through stores (reach L3, visible to all XCDs)
    st_coh((unsigned*)(wh + bglo * HD + ugl0),
           (unsigned)hv[0] | ((unsigned)hv[1] << 16));
    st_coh((unsigned*)(wh + 131072 + bglo * HD + ugl0),
           (unsigned)lv[0] | ((unsigned)lv[1] << 16));
    if (t == TT - 1) {
      float2 hv2 = make_float2(hval[0], hval[1]);
      *(float2*)(out + 256 + bglo * HD + ugl0) = hv2;
    }

    // ---- publish: drain stores to coherence point, then set own flag ----
    asm volatile("s_waitcnt vmcnt(0)" ::: "memory");
    __syncthreads();
    if (tid == 0)
      __hip_atomic_store(my_flag, (unsigned)(t + 1), __ATOMIC_RELAXED,
                         __HIP_MEMORY_SCOPE_AGENT);
  }
}

__global__ __launch_bounds__(256) void logits_k(const float* __restrict__ fcw,
                                                const float* __restrict__ fcb,
                                                float* __restrict__ out) {
  const int b = blockIdx.x * 4 + (threadIdx.x >> 6);
  const int lane = threadIdx.x & 63;
  const float* h = out + 256 + b * HD;
  float s = 0.f;
#pragma unroll
  for (int u = 0; u < 8; ++u) s += h[lane + u * 64] * fcw[lane + u * 64];
#pragma unroll
  for (int off = 32; off > 0; off >>= 1) s += __shfl_down(s, off, 64);
  if (lane == 0) out[b] = s + fcb[0];
}

extern "C" void kernel_launch(void* const* d_in, const int* in_sizes, int n_in,
                              void* d_out, int out_size, void* d_ws, size_t ws_size,
                              hipStream_t stream) {
  (void)in_sizes; (void)n_in; (void)out_size; (void)ws_size;
  const int* X        = (const int*)d_in[0];
  // d_in[1] = M (all-ones mask, unused by reference)
  const float* deltas = (const float*)d_in[2];
  const float* emb    = (const float*)d_in[3];
  const float* Ww     = (const float*)d_in[4];
  const float* Wb     = (const float*)d_in[5];
  const float* Uw     = (const float*)d_in[6];
  const float* Ub     = (const float*)d_in[7];
  const float* Wdw    = (const float*)d_in[8];
  const float* Wdb    = (const float*)d_in[9];
  const float* Udw    = (const float*)d_in[10];
  const float* Udb    = (const float*)d_in[11];
  const float* fcw    = (const float*)d_in[12];
  const float* fcb    = (const float*)d_in[13];
  float* out          = (float*)d_out;

  unsigned short* hbuf  = (unsigned short*)d_ws;
  unsigned int*   flags = (unsigned int*)((char*)d_ws + (1 << 20));

  // zero h buffer 0 (hi+lo) and the flags
  (void)hipMemsetAsync(d_ws, 0, 524288, stream);
  (void)hipMemsetAsync((char*)d_ws + (1 << 20), 0, 4096, stream);

  // Plain launch: 256 WGs <= 256 CUs, each fits (LDS 41KB, <=512 VGPR/wave),
  // so all WGs are resident and the inter-WG spin barrier cannot starve.
  hipLaunchKernelGGL(talstm_scan, dim3(256), dim3(256), 0, stream,
                     X, deltas, emb, Ww, Wb, Uw, Ub, Wdw, Wdb, Udw, Udb,
                     out, hbuf, flags);
  hipLaunchKernelGGL(logits_k, dim3(64), dim3(256), 0, stream, fcw, fcb, out);
}

// Round 8
// 2991.329 us; speedup vs baseline: 7.0777x; 1.3316x over previous
//
#include <hip/hip_runtime.h>

// Time-aware LSTM, persistent-RNN design for MI355X.
// 256 WGs (1/CU) x 256 threads. WG(bg,ug): batches [bg*32,+32), units [ug*16,+16).
// Weights register-resident as MFMA B-fragments (bf16 hi/lo).
// h exchange: coherent sc0/sc1 ops at the XCD-shared L3 (no fences -- R5/R6).
// R7: h loads are COALESCED (1KB/row dwordx4, 16 inst/wave, 8 lines each)
// into an XOR-swizzled LDS stage (swizzle applied on the GLOBAL source,
// LDS dest linear); MFMA fragments come from ds_read_b128. This replaces the
// scattered per-lane 16B sc1 loads (64 lines/inst) that starved L3.

using short8 = __attribute__((ext_vector_type(8))) short;
using f32x4  = __attribute__((ext_vector_type(4))) float;

#define TT 512
#define HD 512
#define ED 256

__device__ __forceinline__ short f2bf(float f) {
  unsigned u = __builtin_bit_cast(unsigned, f);
  u = (u + 0x7FFFu + ((u >> 16) & 1u)) >> 16;
  return (short)u;
}
__device__ __forceinline__ float bf2f(short s) {
  unsigned u = ((unsigned)(unsigned short)s) << 16;
  return __builtin_bit_cast(float, u);
}
__device__ __forceinline__ float sigm(float x) { return 1.f / (1.f + __expf(-x)); }
__device__ __forceinline__ float softplusf_(float x) {
  return fmaxf(x, 0.f) + log1pf(__expf(-fabsf(x)));
}

// Coherent (device-scope, L1/L2-bypassing) 16B load / 4B store.
__device__ __forceinline__ short8 ld_cohx4(const unsigned short* p) {
  short8 v;
  asm volatile("global_load_dwordx4 %0, %1, off sc0 sc1"
               : "=v"(v) : "v"(p) : "memory");
  return v;
}
__device__ __forceinline__ void st_coh(unsigned* p, unsigned v) {
  asm volatile("global_store_dword %0, %1, off sc0 sc1"
               :: "v"(p), "v"(v) : "memory");
}

__global__ __launch_bounds__(256, 1) void talstm_scan(
    const int* __restrict__ X, const float* __restrict__ deltas,
    const float* __restrict__ emb,
    const float* __restrict__ Ww, const float* __restrict__ Wb,
    const float* __restrict__ Uw, const float* __restrict__ Ub,
    const float* __restrict__ Wdw, const float* __restrict__ Wdb,
    const float* __restrict__ Udw, const float* __restrict__ Udb,
    float* __restrict__ out, unsigned short* __restrict__ hbuf,
    unsigned int* __restrict__ flags) {
  __shared__ float zp[4][32][81];            // k-partial z sums
  __shared__ unsigned char stgb[2][32][1024]; // h stage [hi/lo][batch][1KB row], swizzled

  const int tid  = threadIdx.x;
  const int wv   = tid >> 6;   // wave 0..3 (k-slice owner)
  const int lane = tid & 63;
  const int l15  = lane & 15;
  const int l4   = lane >> 4;  // 0..3
  const int bg   = blockIdx.x & 7;
  const int ug   = blockIdx.x >> 3;
  const int b0   = bg * 32;
  const int u0   = ug * 16;

  // ---------------- weight fragments (register resident, loaded once) --------
  short8 Bhh[5][4], Bhl[5][4], Bx[5][2];
#pragma unroll
  for (int g = 0; g < 5; ++g) {
#pragma unroll
    for (int kit = 0; kit < 4; ++kit) {
      short8 hi, lo;
#pragma unroll
      for (int j = 0; j < 8; ++j) {
        const int kr = wv * 128 + kit * 32 + l4 * 8 + j;
        const float f = (g < 4) ? Uw[kr * 2048 + g * 512 + u0 + l15]
                                : Udw[kr * 512 + u0 + l15];
        const short h16 = f2bf(f);
        hi[j] = h16;
        lo[j] = f2bf(f - bf2f(h16));
      }
      Bhh[g][kit] = hi;
      Bhl[g][kit] = lo;
    }
#pragma unroll
    for (int kit = 0; kit < 2; ++kit) {
      short8 v;
#pragma unroll
      for (int j = 0; j < 8; ++j) {
        const int kr = wv * 64 + kit * 32 + l4 * 8 + j;
        const float f = (g < 4) ? Ww[kr * 2048 + g * 512 + u0 + l15]
                                : Wdw[kr * 512 + u0 + l15];
        v[j] = f2bf(f);
      }
      Bx[g][kit] = v;
    }
  }

  // ---------------- per-thread elementwise state -----------------------------
  const int pb0  = (tid * 2) >> 4;  // 0..31
  const int pu0  = (tid * 2) & 15;  // even
  const int bglo = b0 + pb0;
  const int ugl0 = u0 + pu0;
  float bias[2][5];
  float cst[2] = {0.f, 0.f};
#pragma unroll
  for (int p = 0; p < 2; ++p) {
    const int ugl = ugl0 + p;
#pragma unroll
    for (int g = 0; g < 4; ++g)
      bias[p][g] = Wb[g * 512 + ugl] + Ub[g * 512 + ugl];
    bias[p][4] = Wdb[ugl] + Udb[ugl];
  }

  unsigned int* grp_flags = flags + bg * 32;  // 32 flags = one 128B line
  unsigned int* my_flag   = flags + bg * 32 + ug;

  // x fragments for t = 0 (prefetched thereafter)
  short8 ax[2][2];
#pragma unroll
  for (int m = 0; m < 2; ++m) {
    const int b = b0 + m * 16 + l15;
    const int xi = X[b * TT + 0];
    const float* er = emb + (size_t)xi * ED + wv * 64 + l4 * 8;
#pragma unroll
    for (int kit = 0; kit < 2; ++kit) {
      f32x4 f0 = *(const f32x4*)(er + kit * 32);
      f32x4 f1 = *(const f32x4*)(er + kit * 32 + 4);
      short8 v;
      v[0] = f2bf(f0[0]); v[1] = f2bf(f0[1]); v[2] = f2bf(f0[2]); v[3] = f2bf(f0[3]);
      v[4] = f2bf(f1[0]); v[5] = f2bf(f1[1]); v[6] = f2bf(f1[2]); v[7] = f2bf(f1[3]);
      ax[m][kit] = v;
    }
  }

  for (int t = 0; t < TT; ++t) {
    // ---- all-wave poll: group's 32 WGs finished step t-1 (relaxed loads) ----
    if (t > 0) {
      const unsigned tgt = (unsigned)t;
      for (;;) {
        unsigned v = tgt;
        if (lane < 32)
          v = __hip_atomic_load(grp_flags + lane, __ATOMIC_RELAXED,
                                __HIP_MEMORY_SCOPE_AGENT);
        if (__all(v >= tgt)) break;
        __builtin_amdgcn_s_sleep(1);
      }
    }

    // ---- issue coalesced h loads (this wave stages batches wv*8..+8) ----
    // LDS dest linear (lane*16); swizzle applied to the GLOBAL source index:
    // LDS[bb][x] = G[bb][x ^ ((bb&7)<<4)]  (byte offsets within a 1KB row).
    const unsigned short* hh = hbuf + (size_t)(t & 1) * 262144;
    const unsigned short* hl = hh + 131072;
    short8 sreg[16];
#pragma unroll
    for (int i = 0; i < 8; ++i) {
      const int bb = wv * 8 + i;
      const int koff = (lane * 8) ^ ((bb & 7) << 3);  // element index
      sreg[i]     = ld_cohx4(hh + (b0 + bb) * HD + koff);
      sreg[i + 8] = ld_cohx4(hl + (b0 + bb) * HD + koff);
    }

    // ---- x contribution while h loads are in flight ----
    f32x4 acc[2][5];
#pragma unroll
    for (int m = 0; m < 2; ++m)
#pragma unroll
      for (int g = 0; g < 5; ++g) {
        f32x4 z0 = {0.f, 0.f, 0.f, 0.f};
        acc[m][g] = z0;
      }
#pragma unroll
    for (int kit = 0; kit < 2; ++kit)
#pragma unroll
      for (int m = 0; m < 2; ++m)
#pragma unroll
        for (int g = 0; g < 5; ++g)
          acc[m][g] = __builtin_amdgcn_mfma_f32_16x16x32_bf16(
              ax[m][kit], Bx[g][kit], acc[m][g], 0, 0, 0);
    __builtin_amdgcn_sched_barrier(0);
    asm volatile("s_waitcnt vmcnt(0)" ::: "memory");
    __builtin_amdgcn_sched_barrier(0);

    // ---- write stage to LDS (linear dest) ----
#pragma unroll
    for (int i = 0; i < 8; ++i) {
      const int bb = wv * 8 + i;
      *(short8*)&stgb[0][bb][lane * 16] = sreg[i];
      *(short8*)&stgb[1][bb][lane * 16] = sreg[i + 8];
    }

    // ---- issue emb gather for t+1 (convert later, under elementwise) ----
    f32x4 pf[2][2][2];
    if (t + 1 < TT) {
#pragma unroll
      for (int m = 0; m < 2; ++m) {
        const int b = b0 + m * 16 + l15;
        const int xi = X[b * TT + (t + 1)];
        const float* er = emb + (size_t)xi * ED + wv * 64 + l4 * 8;
#pragma unroll
        for (int kit = 0; kit < 2; ++kit) {
          pf[m][kit][0] = *(const f32x4*)(er + kit * 32);
          pf[m][kit][1] = *(const f32x4*)(er + kit * 32 + 4);
        }
      }
    }
    __syncthreads();  // stage complete (all waves)

    // ---- read h fragments from LDS (swizzled) and run h-MFMAs ----
    short8 ahh[2][4], ahl[2][4];
#pragma unroll
    for (int m = 0; m < 2; ++m) {
      const int bb = m * 16 + l15;
#pragma unroll
      for (int kit = 0; kit < 4; ++kit) {
        ahh[m][kit] = *(short8*)&stgb[0][bb][(wv * 256 + kit * 64 + l4 * 16) ^ ((bb & 7) << 4)];
        ahl[m][kit] = *(short8*)&stgb[1][bb][(wv * 256 + kit * 64 + l4 * 16) ^ ((bb & 7) << 4)];
      }
    }

#pragma unroll
    for (int kit = 0; kit < 4; ++kit) {
#pragma unroll
      for (int m = 0; m < 2; ++m)
#pragma unroll
        for (int g = 0; g < 5; ++g)
          acc[m][g] = __builtin_amdgcn_mfma_f32_16x16x32_bf16(
              ahh[m][kit], Bhh[g][kit], acc[m][g], 0, 0, 0);
#pragma unroll
      for (int m = 0; m < 2; ++m)
#pragma unroll
        for (int g = 0; g < 5; ++g)
          acc[m][g] = __builtin_amdgcn_mfma_f32_16x16x32_bf16(
              ahl[m][kit], Bhh[g][kit], acc[m][g], 0, 0, 0);
#pragma unroll
      for (int m = 0; m < 2; ++m)
#pragma unroll
        for (int g = 0; g < 5; ++g)
          acc[m][g] = __builtin_amdgcn_mfma_f32_16x16x32_bf16(
              ahh[m][kit], Bhl[g][kit], acc[m][g], 0, 0, 0);
    }

    // ---- write k-partials to LDS ----
#pragma unroll
    for (int m = 0; m < 2; ++m)
#pragma unroll
      for (int g = 0; g < 5; ++g)
#pragma unroll
        for (int r = 0; r < 4; ++r)
          zp[wv][m * 16 + l4 * 4 + r][g * 16 + l15] = acc[m][g][r];
    __syncthreads();

    // ---- convert prefetched x for t+1 (loads returned under MFMA phase) ----
    if (t + 1 < TT) {
#pragma unroll
      for (int m = 0; m < 2; ++m)
#pragma unroll
        for (int kit = 0; kit < 2; ++kit) {
          f32x4 f0 = pf[m][kit][0];
          f32x4 f1 = pf[m][kit][1];
          short8 v;
          v[0] = f2bf(f0[0]); v[1] = f2bf(f0[1]); v[2] = f2bf(f0[2]); v[3] = f2bf(f0[3]);
          v[4] = f2bf(f1[0]); v[5] = f2bf(f1[1]); v[6] = f2bf(f1[2]); v[7] = f2bf(f1[3]);
          ax[m][kit] = v;
        }
    }

    // ---- elementwise LSTM update (f32), 2 adjacent units of one batch ----
    unsigned short* wh = hbuf + (size_t)((t + 1) & 1) * 262144;
    const float dt = deltas[bglo * TT + t];
    unsigned short hv[2], lv[2];
    float hval[2];
#pragma unroll
    for (int p = 0; p < 2; ++p) {
      float z[5];
#pragma unroll
      for (int g = 0; g < 5; ++g) {
        const int cidx = g * 16 + pu0 + p;
        z[g] = zp[0][pb0][cidx] + zp[1][pb0][cidx] + zp[2][pb0][cidx] +
               zp[3][pb0][cidx] + bias[p][g];
      }
      const float ii = sigm(z[0]);
      const float ff = sigm(z[1]);
      const float oo = sigm(z[2]);
      const float gg = tanhf(z[3]);
      const float dd = softplusf_(z[4]);
      const float gamma = __expf(-dd * dt);
      const float c = ff * (gamma * cst[p]) + ii * gg;
      cst[p] = c;
      const float h = oo * tanhf(c);
      hval[p] = h;
      const short hvs = f2bf(h);
      hv[p] = (unsigned short)hvs;
      lv[p] = (unsigned short)f2bf(h - bf2f(hvs));
    }
    // coherent write-through stores (reach L3, visible to all XCDs)
    st_coh((unsigned*)(wh + bglo * HD + ugl0),
           (unsigned)hv[0] | ((unsigned)hv[1] << 16));
    st_coh((unsigned*)(wh + 131072 + bglo * HD + ugl0),
           (unsigned)lv[0] | ((unsigned)lv[1] << 16));
    if (t == TT - 1) {
      float2 hv2 = make_float2(hval[0], hval[1]);
      *(float2*)(out + 256 + bglo * HD + ugl0) = hv2;
    }

    // ---- publish: drain stores to coherence point, then set own flag ----
    asm volatile("s_waitcnt vmcnt(0)" ::: "memory");
    __syncthreads();
    if (tid == 0)
      __hip_atomic_store(my_flag, (unsigned)(t + 1), __ATOMIC_RELAXED,
                         __HIP_MEMORY_SCOPE_AGENT);
  }
}

__global__ __launch_bounds__(256) void logits_k(const float* __restrict__ fcw,
                                                const float* __restrict__ fcb,
                                                float* __restrict__ out) {
  const int b = blockIdx.x * 4 + (threadIdx.x >> 6);
  const int lane = threadIdx.x & 63;
  const float* h = out + 256 + b * HD;
  float s = 0.f;
#pragma unroll
  for (int u = 0; u < 8; ++u) s += h[lane + u * 64] * fcw[lane + u * 64];
#pragma unroll
  for (int off = 32; off > 0; off >>= 1) s += __shfl_down(s, off, 64);
  if (lane == 0) out[b] = s + fcb[0];
}

extern "C" void kernel_launch(void* const* d_in, const int* in_sizes, int n_in,
                              void* d_out, int out_size, void* d_ws, size_t ws_size,
                              hipStream_t stream) {
  (void)in_sizes; (void)n_in; (void)out_size; (void)ws_size;
  const int* X        = (const int*)d_in[0];
  // d_in[1] = M (all-ones mask, unused by reference)
  const float* deltas = (const float*)d_in[2];
  const float* emb    = (const float*)d_in[3];
  const float* Ww     = (const float*)d_in[4];
  const float* Wb     = (const float*)d_in[5];
  const float* Uw     = (const float*)d_in[6];
  const float* Ub     = (const float*)d_in[7];
  const float* Wdw    = (const float*)d_in[8];
  const float* Wdb    = (const float*)d_in[9];
  const float* Udw    = (const float*)d_in[10];
  const float* Udb    = (const float*)d_in[11];
  const float* fcw    = (const float*)d_in[12];
  const float* fcb    = (const float*)d_in[13];
  float* out          = (float*)d_out;

  unsigned short* hbuf  = (unsigned short*)d_ws;
  unsigned int*   flags = (unsigned int*)((char*)d_ws + (1 << 20));

  // zero h buffer 0 (hi+lo) and the flags
  (void)hipMemsetAsync(d_ws, 0, 524288, stream);
  (void)hipMemsetAsync((char*)d_ws + (1 << 20), 0, 4096, stream);

  // Plain launch: 256 WGs <= 256 CUs, each fits (LDS 105KB, <=512 VGPR/wave),
  // so all WGs are resident and the inter-WG spin barrier cannot starve.
  hipLaunchKernelGGL(talstm_scan, dim3(256), dim3(256), 0, stream,
                     X, deltas, emb, Ww, Wb, Uw, Ub, Wdw, Wdb, Udw, Udb,
                     out, hbuf, flags);
  hipLaunchKernelGGL(logits_k, dim3(64), dim3(256), 0, stream, fcw, fcb, out);
}